// Round 3
// baseline (345.636 us; speedup 1.0000x reference)
//
#include <hip/hip_runtime.h>

// S4 layer: B=8, L=4096, D=1024, N=128
// R3: barrier-free GEMM main loops (fragments straight from global; B/Cw are
// L1/L2-resident). LDS only for gemm2's coalesced-store transpose epilogue.
// Scans: CHUNK=64 (shorter chains, 2x waves).

typedef _Float16 half8 __attribute__((ext_vector_type(8)));
typedef _Float16 half4 __attribute__((ext_vector_type(4)));
typedef float f32x4 __attribute__((ext_vector_type(4)));

#define BDIM 8
#define LDIM 4096
#define DDIM 1024
#define NDIM 128
#define MTOT (BDIM * LDIM)       // 32768
#define CHUNK 64
#define NCHUNK (LDIM / CHUNK)    // 64
#define TOTCHUNK (BDIM * NCHUNK) // 512

// ---------------- prep: final_state + convert Bw,Cw to f16 ----------------
__global__ __launch_bounds__(256) void prep(const float* __restrict__ x,
                                            const float* __restrict__ Bw,
                                            const float* __restrict__ Cw,
                                            _Float16* __restrict__ Bwh,
                                            _Float16* __restrict__ Cwh,
                                            float* __restrict__ out) {
    const int blk = blockIdx.x;
    const int t = threadIdx.x;
    if (blk < 128) {
        // final_state: out[b][n] = mean_b' dot(x[b',L-1,:], Bw[n,:])  (exact fp32)
        const int n = blk;
        float s = 0.f;
        const float* br = Bw + n * DDIM;
        for (int b = 0; b < BDIM; ++b) {
            const float* xr = x + ((size_t)b * LDIM + (LDIM - 1)) * DDIM;
            for (int k = t; k < DDIM; k += 256)
                s = fmaf(xr[k], br[k], s);
        }
        __shared__ float red[256];
        red[t] = s;
        __syncthreads();
        for (int off = 128; off > 0; off >>= 1) {
            if (t < off) red[t] += red[t + off];
            __syncthreads();
        }
        if (t == 0) {
            float v = red[0] * 0.125f;
            for (int b = 0; b < BDIM; ++b)
                out[(size_t)MTOT * DDIM + b * NDIM + n] = v;
        }
    } else {
        // convert 262144 fp32 (Bw then Cw) to f16; 64 blocks x 4096 elems
        const int base = (blk - 128) * 4096;
#pragma unroll
        for (int j = 0; j < 4; ++j) {
            int e = base + j * 1024 + t * 4;
            const float* src;
            _Float16* dst;
            if (e < 131072) { src = Bw + e; dst = Bwh + e; }
            else            { src = Cw + (e - 131072); dst = Cwh + (e - 131072); }
            float4 v = *reinterpret_cast<const float4*>(src);
            half4 h = { (_Float16)v.x, (_Float16)v.y, (_Float16)v.z, (_Float16)v.w };
            *reinterpret_cast<half4*>(dst) = h;
        }
    }
}

// ---------------- GEMM1: xp[m][n] = sum_k x[m][k] * Bw[n][k] ----------------
// 64x128 tile, no LDS, no barriers. 4 waves (2x2: 32 rows x 64 cols each).
// A frags: 2x float4 global + cvt; B frags: half8 global (Bwh is L1/L2-hot).
__global__ __launch_bounds__(256) void gemm1(const float* __restrict__ x,
                                             const _Float16* __restrict__ Bwh,
                                             float* __restrict__ xp) {
    const int t = threadIdx.x;
    const int row0 = blockIdx.x * 64;
    const int wave = t >> 6, lane = t & 63;
    const int wr = (wave >> 1) * 32, wc = (wave & 1) * 64;
    const int lrow = lane & 15, kq = (lane >> 4) * 8;

    const float* xA0 = x + (size_t)(row0 + wr + lrow) * DDIM + kq;
    const float* xA1 = xA0 + (size_t)16 * DDIM;
    const _Float16* Bb = Bwh + (size_t)(wc + lrow) * DDIM + kq;

    f32x4 acc[2][4] = {};

#pragma unroll 4
    for (int kk = 0; kk < DDIM; kk += 32) {
        half8 af[2];
#pragma unroll
        for (int rt = 0; rt < 2; ++rt) {
            const float* p = (rt ? xA1 : xA0) + kk;
            float4 v0 = *reinterpret_cast<const float4*>(p);
            float4 v1 = *reinterpret_cast<const float4*>(p + 4);
            half8 h;
            h[0] = (_Float16)v0.x; h[1] = (_Float16)v0.y;
            h[2] = (_Float16)v0.z; h[3] = (_Float16)v0.w;
            h[4] = (_Float16)v1.x; h[5] = (_Float16)v1.y;
            h[6] = (_Float16)v1.z; h[7] = (_Float16)v1.w;
            af[rt] = h;
        }
#pragma unroll
        for (int ct = 0; ct < 4; ++ct) {
            half8 bf = *reinterpret_cast<const half8*>(Bb + (size_t)ct * 16 * DDIM + kk);
            acc[0][ct] = __builtin_amdgcn_mfma_f32_16x16x32_f16(af[0], bf, acc[0][ct], 0, 0, 0);
            acc[1][ct] = __builtin_amdgcn_mfma_f32_16x16x32_f16(af[1], bf, acc[1][ct], 0, 0, 0);
        }
    }

    // epilogue: xp[m][n]; each store inst covers 4 rows x 64 B segments
    const int q4 = (lane >> 4) * 4;
#pragma unroll
    for (int rt = 0; rt < 2; ++rt)
#pragma unroll
        for (int ct = 0; ct < 4; ++ct) {
            int col = wc + ct * 16 + lrow;
#pragma unroll
            for (int i = 0; i < 4; ++i)
                xp[(row0 + wr + rt * 16 + q4 + i) * NDIM + col] = acc[rt][ct][i];
        }
}

// ---------------- scan phase 1: per-chunk aggregates (chain=64) ----------------
__global__ void scan_agg(const float* __restrict__ xp, const float* __restrict__ logA,
                         float* __restrict__ agg) {
    const int chunk = blockIdx.x;   // 512
    const int n = threadIdx.x;      // 128
    const float A = expf(logA[n]);
    const float* u = xp + chunk * CHUNK * NDIM + n;
    float h = 0.f;
#pragma unroll 16
    for (int j = 0; j < CHUNK; ++j)
        h = fmaf(A, h, u[j * NDIM]);
    agg[chunk * NDIM + n] = h;
}

// ---------------- scan phase 2: carries across 64 chunks ----------------
__global__ void scan_carry(const float* __restrict__ agg, const float* __restrict__ logA,
                           float* __restrict__ hprev) {
    const int idx = blockIdx.x * blockDim.x + threadIdx.x;  // 1024
    const int b = idx >> 7, n = idx & 127;
    const float Ac = expf((float)CHUNK * logA[n]);
    float c = 0.f;
#pragma unroll 8
    for (int ch = 0; ch < NCHUNK; ++ch) {
        int g = (b * NCHUNK + ch) * NDIM + n;
        hprev[g] = c;
        c = fmaf(Ac, c, agg[g]);
    }
}

// ---------------- scan phase 3: final scan, write hs (f16) ----------------
__global__ void scan_final(const float* __restrict__ xp, const float* __restrict__ logA,
                           const float* __restrict__ hprev, _Float16* __restrict__ hs) {
    const int chunk = blockIdx.x;   // 512
    const int n = threadIdx.x;
    const float A = expf(logA[n]);
    float h = hprev[chunk * NDIM + n];
    const float* u = xp + chunk * CHUNK * NDIM + n;
    _Float16* o = hs + chunk * CHUNK * NDIM + n;
#pragma unroll 16
    for (int j = 0; j < CHUNK; ++j) {
        h = fmaf(A, h, u[j * NDIM]);
        o[j * NDIM] = (_Float16)h;
    }
}

// ---------------- GEMM2: y[m][d] = sum_n hs[m][n]*Cw[d][n] + x[m][d]*Dp[d] ----------------
// 128x128 tile, K=128. No staging: half8 fragment loads straight from global
// (hs/Cwh lane-contiguous 16 B, L1/L2-hot). LDS only for transpose epilogue.
#define BUFW 132
__global__ __launch_bounds__(256) void gemm2(const _Float16* __restrict__ hs,
                                             const _Float16* __restrict__ Cwh,
                                             const float* __restrict__ x,
                                             const float* __restrict__ Dp,
                                             float* __restrict__ y) {
    __shared__ float buf[64 * BUFW];   // 33.8 KB
    const int t = threadIdx.x;
    const int row0 = blockIdx.x * 128;
    const int col0 = blockIdx.y * 128;
    const int wave = t >> 6, lane = t & 63;
    const int wr = (wave >> 1) * 64, wc = (wave & 1) * 64;
    const int lrow = lane & 15, kq = (lane >> 4) * 8;

    const _Float16* Ab = hs + (size_t)(row0 + wr + lrow) * NDIM + kq;
    const _Float16* Bb = Cwh + (size_t)(col0 + wc + lrow) * NDIM + kq;

    f32x4 acc[4][4] = {};
#pragma unroll
    for (int kb = 0; kb < 4; ++kb) {
        half8 af[4], bf[4];
#pragma unroll
        for (int rt = 0; rt < 4; ++rt)
            af[rt] = *reinterpret_cast<const half8*>(Ab + (size_t)rt * 16 * NDIM + kb * 32);
#pragma unroll
        for (int ct = 0; ct < 4; ++ct)
            bf[ct] = *reinterpret_cast<const half8*>(Bb + (size_t)ct * 16 * NDIM + kb * 32);
#pragma unroll
        for (int rt = 0; rt < 4; ++rt)
#pragma unroll
            for (int ct = 0; ct < 4; ++ct)
                acc[rt][ct] = __builtin_amdgcn_mfma_f32_16x16x32_f16(af[rt], bf[ct], acc[rt][ct], 0, 0, 0);
    }

    // Dp for this thread's epilogue columns (constant across j: (t+256j)&31 == t&31)
    float4 dp = *reinterpret_cast<const float4*>(&Dp[col0 + (t & 31) * 4]);

    // epilogue: two 64-row halves through LDS fp32 buffer [64][BUFW]
    const int q4 = (lane >> 4) * 4;
#pragma unroll
    for (int half_ = 0; half_ < 2; ++half_) {
        __syncthreads();
        if ((wr >> 6) == half_) {
#pragma unroll
            for (int rt = 0; rt < 4; ++rt)
#pragma unroll
                for (int ct = 0; ct < 4; ++ct) {
                    int col = wc + ct * 16 + lrow;
#pragma unroll
                    for (int i = 0; i < 4; ++i)
                        buf[(rt * 16 + q4 + i) * BUFW + col] = acc[rt][ct][i];
                }
        }
        __syncthreads();
#pragma unroll
        for (int j = 0; j < 8; ++j) {
            int idx = t + 256 * j;
            int row = idx >> 5, c4 = idx & 31;
            int grow = row0 + half_ * 64 + row;
            float4 a = *reinterpret_cast<const float4*>(&buf[row * BUFW + c4 * 4]);
            float4 xv = *reinterpret_cast<const float4*>(&x[(size_t)grow * DDIM + col0 + c4 * 4]);
            float4 o;
            o.x = a.x + xv.x * dp.x;
            o.y = a.y + xv.y * dp.y;
            o.z = a.z + xv.z * dp.z;
            o.w = a.w + xv.w * dp.w;
            *reinterpret_cast<float4*>(&y[(size_t)grow * DDIM + col0 + c4 * 4]) = o;
        }
    }
}

extern "C" void kernel_launch(void* const* d_in, const int* in_sizes, int n_in,
                              void* d_out, int out_size, void* d_ws, size_t ws_size,
                              hipStream_t stream) {
    const float* x    = (const float*)d_in[0];   // (8, 4096, 1024)
    const float* Bw   = (const float*)d_in[1];   // (128, 1024)
    const float* Cw   = (const float*)d_in[2];   // (1024, 128)
    const float* logA = (const float*)d_in[3];   // (128,)
    const float* Dp   = (const float*)d_in[4];   // (1024,)
    float* out = (float*)d_out;                  // y (33554432) + final_state (1024)

    char* ws = (char*)d_ws;
    float*    xp    = (float*)   (ws);                 // 16,777,216 B
    _Float16* hs    = (_Float16*)(ws + 16777216);      //  8,388,608 B
    float*    agg   = (float*)   (ws + 25165824);      //    262,144 B
    float*    hprev = (float*)   (ws + 25427968);      //    262,144 B
    _Float16* Bwh   = (_Float16*)(ws + 25690112);      //    262,144 B
    _Float16* Cwh   = (_Float16*)(ws + 25952256);      //    262,144 B

    prep<<<192, 256, 0, stream>>>(x, Bw, Cw, Bwh, Cwh, out);
    gemm1<<<MTOT / 64, 256, 0, stream>>>(x, Bwh, xp);
    scan_agg<<<TOTCHUNK, 128, 0, stream>>>(xp, logA, agg);
    scan_carry<<<4, 256, 0, stream>>>(agg, logA, hprev);
    scan_final<<<TOTCHUNK, 128, 0, stream>>>(xp, logA, hprev, hs);
    gemm2<<<dim3(MTOT / 128, DDIM / 128), 256, 0, stream>>>(hs, Cwh, x, Dp, out);
}